// Round 1
// 249.920 us; speedup vs baseline: 1.0321x; 1.0321x over previous
//
#include <hip/hip_runtime.h>
#include <hip/hip_bf16.h>
#include <stdint.h>

typedef __attribute__((ext_vector_type(8))) __bf16 bf16x8;
typedef __attribute__((ext_vector_type(4))) __bf16 bf16x4;
typedef __attribute__((ext_vector_type(4))) float f32x4;

#define HN 16
#define DM 1024
#define GQ 128
#define SEQ 4096
#define BLK 512
#define SCALE 0.125f
#define NCHUNK 11

#define GLL16(g, l) __builtin_amdgcn_global_load_lds( \
    (__attribute__((address_space(1))) void*)(g), \
    (__attribute__((address_space(3))) void*)(l), 16, 0, 0)

// ---------------- casts ----------------
__global__ void cast_w4(const float* __restrict__ w0, const float* __restrict__ w1,
                        const float* __restrict__ w2, const float* __restrict__ w3,
                        __bf16* __restrict__ out) {
  const float* srcs[4] = {w0, w1, w2, w3};
  const float* src = srcs[blockIdx.y];
  int t = blockIdx.x * 256 + threadIdx.x;
  float4 v = ((const float4*)src)[t];
  bf16x4 o = {(__bf16)v.x, (__bf16)v.y, (__bf16)v.z, (__bf16)v.w};
  ((bf16x4*)(out + (size_t)blockIdx.y * (size_t)(DM * DM)))[t] = o;
}

__global__ void cast_x(const float* __restrict__ in, __bf16* __restrict__ out) {
  int t = blockIdx.x * 256 + threadIdx.x;
  float4 v = ((const float4*)in)[t];
  bf16x4 o = {(__bf16)v.x, (__bf16)v.y, (__bf16)v.z, (__bf16)v.w};
  ((bf16x4*)out)[t] = o;
}

// ---------------- 256x256x32 GEMM, 8 waves, 4-deep ring, counted vmcnt ----
// Per-wave output 128x64 (acc[8][4]); BK=32; LDS = 4 bufs x (A 16KB + B 16KB)
// = 128 KiB -> 1 block/CU, 2 waves/SIMD. Phase split: 2 x 16 MFMA per K-tile,
// stage-issue interleaved (A-halftile in ph0, B in ph1), vmcnt(8) steady state.
__global__ __launch_bounds__(512, 2) void gemm256(
    const __bf16* __restrict__ A, const __bf16* __restrict__ W,
    __bf16* __restrict__ Qt, __bf16* __restrict__ Kt, __bf16* __restrict__ VtT,
    __bf16* __restrict__ Qg, __bf16* __restrict__ Kg, __bf16* __restrict__ VgT,
    float* __restrict__ Cf, int NT, int mode) {
  __shared__ __bf16 As[4][256 * 32];
  __shared__ __bf16 Bs[4][256 * 32];
  int tid = threadIdx.x;
  int lane = tid & 63;
  int wid = tid >> 6;
  int lr = lane & 15, lh = lane >> 4;
  int wm = wid >> 2, wn = wid & 3;  // 2 x 4 wave grid

  int nwg = gridDim.x;
  int q = nwg >> 3, r = nwg & 7;
  int xcd = blockIdx.x & 7, loc = blockIdx.x >> 3;
  int swz = (xcd < r ? xcd * (q + 1) : r * (q + 1) + (xcd - r) * q) + loc;
  int bm = swz / NT, bn = swz - bm * NT;
  long m0 = (long)bm * 256, n0 = (long)bn * 256;
  const __bf16* Ab = A + m0 * 1024;
  const __bf16* Wb2 = W + n0 * 1024;

  // staging geometry: 4 threads/row (32 elems), granule-XOR pre-swizzle on the
  // global source; LDS stays linear (rule 21 both-sides involution).
  int trow = tid >> 2;                          // 0..127
  int gsw = (((tid & 3) ^ (trow & 3)) << 3);    // source element offset

  f32x4 acc[8][4];
#pragma unroll
  for (int i = 0; i < 8; ++i)
#pragma unroll
    for (int j = 0; j < 4; ++j) acc[i][j] = (f32x4){0.f, 0.f, 0.f, 0.f};

  auto stageA = [&](int kt, int bufi) {
    int k0 = kt * 32;
#pragma unroll
    for (int c = 0; c < 2; ++c) {
      int row = c * 128 + trow;
      GLL16(Ab + (long)row * 1024 + k0 + gsw, &As[bufi][(c * 512 + tid) * 8]);
    }
  };
  auto stageB = [&](int kt, int bufi) {
    int k0 = kt * 32;
#pragma unroll
    for (int c = 0; c < 2; ++c) {
      int row = c * 128 + trow;
      GLL16(Wb2 + (long)row * 1024 + k0 + gsw, &Bs[bufi][(c * 512 + tid) * 8]);
    }
  };

  // prologue: 3 K-tiles in flight (12 loads/wave)
  stageA(0, 0); stageB(0, 0);
  stageA(1, 1); stageB(1, 1);
  stageA(2, 2); stageB(2, 2);

#pragma unroll 1
  for (int t = 0; t < 32; ++t) {
    int c = t & 3;
    const __bf16* Ap = As[c];
    const __bf16* Bp = Bs[c];

    // wait for tile t only; tiles t+1,t+2 stay in flight (T4: never 0 mid-loop)
    if (t < 30) asm volatile("s_waitcnt vmcnt(8)" ::: "memory");
    else if (t == 30) asm volatile("s_waitcnt vmcnt(4)" ::: "memory");
    else asm volatile("s_waitcnt vmcnt(0)" ::: "memory");
    __builtin_amdgcn_sched_barrier(0);
    __builtin_amdgcn_s_barrier();
    __builtin_amdgcn_sched_barrier(0);

    // ---- phase 0: rows i0..3, all 4 col-frags ----
    bf16x8 bfr[4], af[4];
#pragma unroll
    for (int j = 0; j < 4; ++j) {
      int cc = wn * 64 + j * 16 + lr;
      bfr[j] = *(const bf16x8*)&Bp[cc * 32 + ((lh ^ (cc & 3)) << 3)];
    }
#pragma unroll
    for (int i = 0; i < 4; ++i) {
      int rr = wm * 128 + i * 16 + lr;
      af[i] = *(const bf16x8*)&Ap[rr * 32 + ((lh ^ (rr & 3)) << 3)];
    }
    if (t < 29) stageA(t + 3, (t + 3) & 3);  // into buf freed at iter t-1
    __builtin_amdgcn_sched_barrier(0);
    __builtin_amdgcn_s_barrier();
    __builtin_amdgcn_sched_barrier(0);
    asm volatile("s_waitcnt lgkmcnt(0)" ::: "memory");
    __builtin_amdgcn_sched_barrier(0);
    __builtin_amdgcn_s_setprio(1);
#pragma unroll
    for (int i = 0; i < 4; ++i)
#pragma unroll
      for (int j = 0; j < 4; ++j)
        acc[i][j] = __builtin_amdgcn_mfma_f32_16x16x32_bf16(af[i], bfr[j],
                                                            acc[i][j], 0, 0, 0);
    __builtin_amdgcn_s_setprio(0);
    __builtin_amdgcn_sched_barrier(0);
    __builtin_amdgcn_s_barrier();
    __builtin_amdgcn_sched_barrier(0);

    // ---- phase 1: rows i4..7, b-frags reused from registers ----
#pragma unroll
    for (int i = 0; i < 4; ++i) {
      int rr = wm * 128 + (i + 4) * 16 + lr;
      af[i] = *(const bf16x8*)&Ap[rr * 32 + ((lh ^ (rr & 3)) << 3)];
    }
    if (t < 29) stageB(t + 3, (t + 3) & 3);
    asm volatile("s_waitcnt lgkmcnt(0)" ::: "memory");
    __builtin_amdgcn_sched_barrier(0);
    __builtin_amdgcn_s_setprio(1);
#pragma unroll
    for (int i = 0; i < 4; ++i)
#pragma unroll
      for (int j = 0; j < 4; ++j)
        acc[i + 4][j] = __builtin_amdgcn_mfma_f32_16x16x32_bf16(af[i], bfr[j],
                                                                acc[i + 4][j], 0, 0, 0);
    __builtin_amdgcn_s_setprio(0);
  }

  if (mode == 1) {
#pragma unroll
    for (int i = 0; i < 8; ++i) {
      long row0 = m0 + wm * 128 + i * 16 + lh * 4;
#pragma unroll
      for (int j = 0; j < 4; ++j) {
        int col = (int)n0 + wn * 64 + j * 16 + lr;
#pragma unroll
        for (int jj = 0; jj < 4; ++jj) Cf[(row0 + jj) * 1024 + col] = acc[i][j][jj];
      }
    }
  } else {
    int tok = m0 < 8192;  // M=8448=32*256 token + 1*256 global: tiles never span
#pragma unroll
    for (int i = 0; i < 8; ++i) {
#pragma unroll
      for (int j = 0; j < 4; ++j) {
        int col = (int)n0 + wn * 64 + j * 16 + lr;
        int z = col >> 10, hc = col & 1023;
        int h = hc >> 6, f = hc & 63;
#pragma unroll
        for (int jj = 0; jj < 4; ++jj) {
          long row = m0 + wm * 128 + i * 16 + lh * 4 + jj;
          __bf16 v = (__bf16)acc[i][j][jj];
          if (tok) {
            int b = (int)(row >> 12), l = (int)(row & 4095);
            long bh = b * HN + h;
            if (z == 0) Qt[(bh * SEQ + l) * 64 + f] = v;
            else if (z == 1) Kt[(bh * SEQ + l) * 64 + f] = v;
            else VtT[(bh * 64 + f) * SEQ + l] = v;
          } else {
            int gr = (int)(row - 8192);
            int b = gr >> 7, l = gr & 127;
            long bh = b * HN + h;
            if (z == 0) Qg[(bh * GQ + l) * 64 + f] = v;
            else if (z == 1) Kg[(bh * GQ + l) * 64 + f] = v;
            else VgT[(bh * 64 + f) * GQ + l] = v;
          }
        }
      }
    }
  }
}

// ---------------- fused flash attention, swapped-QK^T softmax ----------------
__global__ __launch_bounds__(256) void attn_kernel(
    const __bf16* __restrict__ Qt, const __bf16* __restrict__ Qg,
    const __bf16* __restrict__ Kg, const __bf16* __restrict__ VgT,
    const __bf16* __restrict__ Kt, const __bf16* __restrict__ VtT,
    const float* __restrict__ mask,
    __bf16* __restrict__ AL, float* __restrict__ Opart, float* __restrict__ Ml) {
  __shared__ __bf16 Ks[2][64 * 64];
  __shared__ __bf16 Vs[2][64 * 64];
  __shared__ __bf16 Ps[128 * 64];

  int bid = blockIdx.x;
  int tid = threadIdx.x, wid = tid >> 6, lane = tid & 63;
  int lr = lane & 15, lh = lane >> 4;

  int isLocal = bid < 1024;
  int unit, q0, tgoff, tokbase, ntiles, pidx = 0;
  if (isLocal) {
    unit = bid >> 5;
    q0 = (bid & 31) << 7;
    tgoff = 0;
    tokbase = q0 & ~(BLK - 1);
    ntiles = 10;
  } else {
    int x = bid - 1024;
    unit = x / NCHUNK;
    int chunk = x - unit * NCHUNK;
    q0 = 0;
    tgoff = chunk * 6;
    tokbase = 0;
    ntiles = 6;
    pidx = x;
  }
  int b = unit >> 4, h = unit & 15;
  long bh = unit;
  const __bf16* Qbase = isLocal ? Qt + (bh * SEQ + q0) * 64 : Qg + bh * GQ * 64;

  bf16x8 qf[2][2];
#pragma unroll
  for (int m = 0; m < 2; m++)
#pragma unroll
    for (int ks = 0; ks < 2; ks++)
      qf[m][ks] = *(const bf16x8*)&Qbase[(wid * 32 + m * 16 + lr) * 64 + ks * 32 + lh * 8];

  float mrun[2], lrun[2];
  f32x4 oacc[2][4];
#pragma unroll
  for (int m = 0; m < 2; m++) {
    mrun[m] = -__builtin_inff();
    lrun[m] = 0.f;
#pragma unroll
    for (int n = 0; n < 4; n++) oacc[m][n] = (f32x4){0.f, 0.f, 0.f, 0.f};
  }

  int c0 = (lane & 7) * 8;
  int ssw = ((wid * 2 + (lane >> 5)) & 3) << 4;
  int rxor = 2 * ((lr >> 2) & 3);

  auto stage = [&](int t, int bb) {
    int tg = t + tgoff;
    int glob = tg < 2;
    int kpos0 = glob ? tg * 64 : tokbase + (tg - 2) * 64;
    const __bf16* Kp = glob ? Kg + (bh * GQ + kpos0) * 64 : Kt + (bh * SEQ + kpos0) * 64;
    const __bf16* Vp = glob ? VgT + bh * 64 * GQ + kpos0 : VtT + bh * 64 * SEQ + kpos0;
    long vstr = glob ? GQ : SEQ;
#pragma unroll
    for (int s = 0; s < 2; ++s) {
      int r = s * 32 + wid * 8 + (lane >> 3);
      GLL16(Kp + (long)r * 64 + (c0 ^ ssw), &Ks[bb][(s * 256 + wid * 64) * 8]);
      GLL16(Vp + (long)r * vstr + (c0 ^ ssw), &Vs[bb][(s * 256 + wid * 64) * 8]);
    }
  };

  stage(0, 0);

  for (int t = 0; t < ntiles; ++t) {
    int bb = t & 1;
    int tg = t + tgoff;
    int glob = tg < 2;
    int kpos0 = glob ? tg * 64 : tokbase + (tg - 2) * 64;

    __syncthreads();
    if (t + 1 < ntiles) stage(t + 1, bb ^ 1);

    f32x4 sacc[4][2];
#pragma unroll
    for (int n = 0; n < 4; n++)
#pragma unroll
      for (int m = 0; m < 2; m++) sacc[n][m] = (f32x4){0.f, 0.f, 0.f, 0.f};
#pragma unroll
    for (int ks = 0; ks < 2; ++ks) {
      bf16x8 kf[4];
#pragma unroll
      for (int n = 0; n < 4; n++)
        kf[n] = *(const bf16x8*)&Ks[bb][(n * 16 + lr) * 64 + (((ks * 4 + lh) ^ rxor) << 3)];
#pragma unroll
      for (int n = 0; n < 4; n++)
#pragma unroll
        for (int m = 0; m < 2; m++)
          sacc[n][m] = __builtin_amdgcn_mfma_f32_16x16x32_bf16(kf[n], qf[m][ks], sacc[n][m], 0, 0, 0);
    }

    float4 mk[4];
    if (glob) {
#pragma unroll
      for (int n = 0; n < 4; n++) mk[n] = (float4){0.f, 0.f, 0.f, 0.f};
    } else {
#pragma unroll
      for (int n = 0; n < 4; n++)
        mk[n] = *(const float4*)&mask[(long)b * SEQ + kpos0 + n * 16 + lh * 4];
    }

    float alpha[2];
#pragma unroll
    for (int m = 0; m < 2; m++) {
      float mx = -__builtin_inff();
#pragma unroll
      for (int n = 0; n < 4; n++) {
        const float* mkp = &mk[n].x;
#pragma unroll
        for (int j = 0; j < 4; j++) {
          float s = sacc[n][m][j] * SCALE + mkp[j];
          sacc[n][m][j] = s;
          mx = fmaxf(mx, s);
        }
      }
      mx = fmaxf(mx, __shfl_xor(mx, 16));
      mx = fmaxf(mx, __shfl_xor(mx, 32));
      float mnew = fmaxf(mrun[m], mx);
      alpha[m] = __expf(mrun[m] - mnew);
      mrun[m] = mnew;
      float rs = 0.f;
#pragma unroll
      for (int n = 0; n < 4; n++) {
#pragma unroll
        for (int j = 0; j < 4; j++) {
          float p = __expf(sacc[n][m][j] - mnew);
          sacc[n][m][j] = p;
          rs += p;
        }
      }
      rs += __shfl_xor(rs, 16);
      rs += __shfl_xor(rs, 32);
      lrun[m] = lrun[m] * alpha[m] + rs;
    }

#pragma unroll
    for (int m = 0; m < 2; m++) {
      int row = wid * 32 + m * 16 + lr;
#pragma unroll
      for (int n = 0; n < 4; n++) {
        bf16x4 pk = {(__bf16)sacc[n][m][0], (__bf16)sacc[n][m][1],
                     (__bf16)sacc[n][m][2], (__bf16)sacc[n][m][3]};
        int g8 = (n * 2 + (lh >> 1)) ^ rxor;
        *(bf16x4*)&Ps[row * 64 + (g8 << 3) + ((lh & 1) << 2)] = pk;
      }
    }

#pragma unroll
    for (int m = 0; m < 2; m++) {
#pragma unroll
      for (int jj = 0; jj < 4; jj++) {
        float a = __shfl(alpha[m], lh * 4 + jj);
#pragma unroll
        for (int n = 0; n < 4; n++) oacc[m][n][jj] *= a;
      }
    }

#pragma unroll
    for (int ks = 0; ks < 2; ++ks) {
      bf16x8 pf[2], vf[4];
#pragma unroll
      for (int m = 0; m < 2; m++) {
        int row = wid * 32 + m * 16 + lr;
        pf[m] = *(const bf16x8*)&Ps[row * 64 + (((ks * 4 + lh) ^ rxor) << 3)];
      }
#pragma unroll
      for (int n = 0; n < 4; n++)
        vf[n] = *(const bf16x8*)&Vs[bb][(n * 16 + lr) * 64 + (((ks * 4 + lh) ^ rxor) << 3)];
#pragma unroll
      for (int m = 0; m < 2; m++)
#pragma unroll
        for (int n = 0; n < 4; n++)
          oacc[m][n] = __builtin_amdgcn_mfma_f32_16x16x32_bf16(pf[m], vf[n], oacc[m][n], 0, 0, 0);
    }
  }

  if (isLocal) {
#pragma unroll
    for (int m = 0; m < 2; m++) {
#pragma unroll
      for (int jj = 0; jj < 4; jj++) {
        float inv = 1.f / __shfl(lrun[m], lh * 4 + jj);
        int row = q0 + wid * 32 + m * 16 + lh * 4 + jj;
#pragma unroll
        for (int n = 0; n < 4; n++)
          AL[((long)b * SEQ + row) * 1024 + h * 64 + n * 16 + lr] =
              (__bf16)(oacc[m][n][jj] * inv);
      }
    }
  } else {
    float* Op = Opart + (long)pidx * (128 * 64);
#pragma unroll
    for (int m = 0; m < 2; m++) {
      int srow = wid * 32 + m * 16 + lr;
      if (lh == 0) {
        Ml[pidx * 256 + srow] = mrun[m];
        Ml[pidx * 256 + 128 + srow] = lrun[m];
      }
#pragma unroll
      for (int jj = 0; jj < 4; jj++) {
        int row = wid * 32 + m * 16 + lh * 4 + jj;
#pragma unroll
        for (int n = 0; n < 4; n++) Op[row * 64 + n * 16 + lr] = oacc[m][n][jj];
      }
    }
  }
}

// ---------------- combine global-attn partials ----------------
__global__ __launch_bounds__(256) void combine_global(
    const float* __restrict__ Opart, const float* __restrict__ Ml,
    __bf16* __restrict__ AG) {
  int unit = blockIdx.x;
  int b = unit >> 4, h = unit & 15;
  int t = threadIdx.x;
  int row = t >> 1, f0 = (t & 1) * 32;

  float mstar = -__builtin_inff();
#pragma unroll
  for (int c = 0; c < NCHUNK; ++c)
    mstar = fmaxf(mstar, Ml[(unit * NCHUNK + c) * 256 + row]);

  float L = 0.f;
  f32x4 acc[8];
#pragma unroll
  for (int k = 0; k < 8; k++) acc[k] = (f32x4){0.f, 0.f, 0.f, 0.f};

  for (int c = 0; c < NCHUNK; ++c) {
    int idx = unit * NCHUNK + c;
    float w = __expf(Ml[idx * 256 + row] - mstar);
    L += w * Ml[idx * 256 + 128 + row];
    const f32x4* src = (const f32x4*)(Opart + ((long)idx * 128 + row) * 64 + f0);
#pragma unroll
    for (int k = 0; k < 8; k++) acc[k] += src[k] * w;
  }
  float inv = 1.f / L;
  __bf16* dst = AG + ((long)b * GQ + row) * 1024 + h * 64 + f0;
#pragma unroll
  for (int k = 0; k < 8; k++) {
    bf16x4 o = {(__bf16)(acc[k][0] * inv), (__bf16)(acc[k][1] * inv),
                (__bf16)(acc[k][2] * inv), (__bf16)(acc[k][3] * inv)};
    *(bf16x4*)(dst + k * 4) = o;
  }
}

extern "C" void kernel_launch(void* const* d_in, const int* in_sizes, int n_in,
                              void* d_out, int out_size, void* d_ws, size_t ws_size,
                              hipStream_t stream) {
  const float* Xt = (const float*)d_in[0];
  const float* Xg = (const float*)d_in[1];
  const float* Msk = (const float*)d_in[2];
  const float* Wq = (const float*)d_in[3];
  const float* Wk = (const float*)d_in[4];
  const float* Wv = (const float*)d_in[5];
  const float* Wo = (const float*)d_in[6];

  float* outF = (float*)d_out;

  char* ws = (char*)d_ws;
  __bf16* Wb = (__bf16*)ws;  ws += (size_t)4 * DM * DM * 2;
  __bf16* XB = (__bf16*)ws;  ws += (size_t)8448 * DM * 2;
  __bf16* Qt = (__bf16*)ws;  ws += (size_t)2 * SEQ * DM * 2;
  __bf16* Kt = (__bf16*)ws;  ws += (size_t)2 * SEQ * DM * 2;
  __bf16* VtT = (__bf16*)ws; ws += (size_t)2 * SEQ * DM * 2;
  __bf16* Qg = (__bf16*)ws;  ws += (size_t)2 * GQ * DM * 2;
  __bf16* Kg = (__bf16*)ws;  ws += (size_t)2 * GQ * DM * 2;
  __bf16* VgT = (__bf16*)ws; ws += (size_t)2 * GQ * DM * 2;
  __bf16* AB = (__bf16*)ws;  ws += (size_t)8448 * DM * 2;

  __bf16* AL = AB;
  __bf16* AG = AB + (size_t)8192 * DM;

  float* Opart = (float*)XB;
  float* Ml = Opart + (long)32 * NCHUNK * 128 * 64;

  cast_w4<<<dim3(1024, 4), 256, 0, stream>>>(Wq, Wk, Wv, Wo, Wb);
  cast_x<<<dim3(8192), 256, 0, stream>>>(Xt, XB);
  cast_x<<<dim3(256), 256, 0, stream>>>(Xg, XB + (size_t)8192 * DM);

  // QKV projection: M=8448, N=3072, K=1024 -> 33 x 12 tiles
  gemm256<<<dim3(396), 512, 0, stream>>>(XB, Wb, Qt, Kt, VtT, Qg, Kg, VgT,
                                         nullptr, 12, 0);

  attn_kernel<<<dim3(1024 + 32 * NCHUNK), 256, 0, stream>>>(
      Qt, Qg, Kg, VgT, Kt, VtT, Msk, AL, Opart, Ml);

  combine_global<<<dim3(32), 256, 0, stream>>>(Opart, Ml, AG);

  // Output projection: M=8448, N=1024 -> 33 x 4 tiles
  gemm256<<<dim3(132), 512, 0, stream>>>(AB, Wb + (size_t)3 * DM * DM,
                                         nullptr, nullptr, nullptr, nullptr, nullptr,
                                         nullptr, outF, 4, 1);
}

// Round 2
// 246.465 us; speedup vs baseline: 1.0466x; 1.0140x over previous
//
#include <hip/hip_runtime.h>
#include <hip/hip_bf16.h>
#include <stdint.h>

typedef __attribute__((ext_vector_type(8))) __bf16 bf16x8;
typedef __attribute__((ext_vector_type(4))) __bf16 bf16x4;
typedef __attribute__((ext_vector_type(4))) float f32x4;

#define HN 16
#define DM 1024
#define GQ 128
#define SEQ 4096
#define BLK 512
#define SCALE 0.125f
#define NCHUNK 11

#define GLL16(g, l) __builtin_amdgcn_global_load_lds( \
    (__attribute__((address_space(1))) void*)(g), \
    (__attribute__((address_space(3))) void*)(l), 16, 0, 0)

#define SB() __builtin_amdgcn_sched_barrier(0)

// ---------------- casts ----------------
__global__ void cast_w4(const float* __restrict__ w0, const float* __restrict__ w1,
                        const float* __restrict__ w2, const float* __restrict__ w3,
                        __bf16* __restrict__ out) {
  const float* srcs[4] = {w0, w1, w2, w3};
  const float* src = srcs[blockIdx.y];
  int t = blockIdx.x * 256 + threadIdx.x;
  float4 v = ((const float4*)src)[t];
  bf16x4 o = {(__bf16)v.x, (__bf16)v.y, (__bf16)v.z, (__bf16)v.w};
  ((bf16x4*)(out + (size_t)blockIdx.y * (size_t)(DM * DM)))[t] = o;
}

__global__ void cast_x(const float* __restrict__ in, __bf16* __restrict__ out) {
  int t = blockIdx.x * 256 + threadIdx.x;
  float4 v = ((const float4*)in)[t];
  bf16x4 o = {(__bf16)v.x, (__bf16)v.y, (__bf16)v.z, (__bf16)v.w};
  ((bf16x4*)out)[t] = o;
}

// ---------------- 256x256x64 GEMM, 8 waves, dbuf, counted vmcnt/lgkmcnt ----
// BK=64 (128B rows = 32-bank stride) + proven XOR-8 involution swizzle -> 0
// bank conflicts. 4 MFMA-phases/K-tile (16 each), ds_reads one phase ahead
// with counted lgkmcnt; stageA before head vmcnt(4) so loads never drain to 0
// mid-loop. 2 s_barrier per K-tile (head: staging visible; tail: reads done).
__global__ __launch_bounds__(512, 2) void gemm256(
    const __bf16* __restrict__ A, const __bf16* __restrict__ W,
    __bf16* __restrict__ Qt, __bf16* __restrict__ Kt, __bf16* __restrict__ VtT,
    __bf16* __restrict__ Qg, __bf16* __restrict__ Kg, __bf16* __restrict__ VgT,
    float* __restrict__ Cf, int NT, int mode) {
  __shared__ __bf16 As[2][256 * 64];
  __shared__ __bf16 Bs[2][256 * 64];
  int tid = threadIdx.x;
  int lane = tid & 63;
  int wid = tid >> 6;
  int lr = lane & 15, lh = lane >> 4;
  int wm = wid >> 2, wn = wid & 3;  // 2 x 4 wave grid, per-wave 128x64 output

  int nwg = gridDim.x;
  int q = nwg >> 3, r = nwg & 7;
  int xcd = blockIdx.x & 7, loc = blockIdx.x >> 3;
  int swz = (xcd < r ? xcd * (q + 1) : r * (q + 1) + (xcd - r) * q) + loc;
  int bm = swz / NT, bn = swz - bm * NT;
  long m0 = (long)bm * 256, n0 = (long)bn * 256;
  const __bf16* Ab = A + m0 * 1024;
  const __bf16* Wb2 = W + n0 * 1024;

  // staging: 8 threads/row (64 elems = 8 x 16B granules); source pre-swizzled
  // by granule ^= row&7, LDS linear (involution matches read side).
  int srow = tid >> 3;                          // 0..63
  int scol = (((tid & 7) ^ (srow & 7)) << 3);   // element offset in source row

  f32x4 acc[8][4];
#pragma unroll
  for (int i = 0; i < 8; ++i)
#pragma unroll
    for (int j = 0; j < 4; ++j) acc[i][j] = (f32x4){0.f, 0.f, 0.f, 0.f};

  auto stageA = [&](int kt, int p) {
    int k0 = kt * 64;
#pragma unroll
    for (int c = 0; c < 4; ++c) {
      int row = c * 64 + srow;
      GLL16(Ab + (long)row * 1024 + k0 + scol, &As[p][(c * 512 + tid) * 8]);
    }
  };
  auto stageB = [&](int kt, int p) {
    int k0 = kt * 64;
#pragma unroll
    for (int c = 0; c < 4; ++c) {
      int row = c * 64 + srow;
      GLL16(Wb2 + (long)row * 1024 + k0 + scol, &Bs[p][(c * 512 + tid) * 8]);
    }
  };

  stageA(0, 0);
  stageB(0, 0);

#pragma unroll 1
  for (int t = 0; t < 16; ++t) {
    int p = t & 1;
    const __bf16* Ap = As[p];
    const __bf16* Bp = Bs[p];

    if (t < 15) {
      stageA(t + 1, p ^ 1);  // into buf whose reads finished last tile
      asm volatile("s_waitcnt vmcnt(4)" ::: "memory");  // tile t landed, 4 in flight
    } else {
      asm volatile("s_waitcnt vmcnt(0)" ::: "memory");
    }
    SB();
    __builtin_amdgcn_s_barrier();  // head: all waves' staging of buf p visible
    SB();

    bf16x8 a0[4], a1[4], b0[4], b1[4];
    // ph0 frags: B[ks=0] + A[rows 0..3, ks=0]   (8 ds_read_b128)
#pragma unroll
    for (int j = 0; j < 4; ++j) {
      int cc = wn * 64 + j * 16 + lr;
      b0[j] = *(const bf16x8*)&Bp[cc * 64 + ((lh ^ (cc & 7)) << 3)];
    }
#pragma unroll
    for (int i = 0; i < 4; ++i) {
      int rr = wm * 128 + i * 16 + lr;
      a0[i] = *(const bf16x8*)&Ap[rr * 64 + ((lh ^ (rr & 7)) << 3)];
    }
    SB();
    // ph1 A-frags: rows 4..7, ks=0   (4 ds_read_b128)
#pragma unroll
    for (int i = 0; i < 4; ++i) {
      int rr = wm * 128 + (i + 4) * 16 + lr;
      a1[i] = *(const bf16x8*)&Ap[rr * 64 + ((lh ^ (rr & 7)) << 3)];
    }
    SB();
    if (t < 15) stageB(t + 1, p ^ 1);
    SB();
    asm volatile("s_waitcnt lgkmcnt(4)" ::: "memory");  // ph0's 8 done
    SB();
    __builtin_amdgcn_s_setprio(1);
#pragma unroll
    for (int i = 0; i < 4; ++i)
#pragma unroll
      for (int j = 0; j < 4; ++j)
        acc[i][j] = __builtin_amdgcn_mfma_f32_16x16x32_bf16(a0[i], b0[j],
                                                            acc[i][j], 0, 0, 0);
    __builtin_amdgcn_s_setprio(0);
    SB();
    // ph2 frags: B[ks=1] + A[rows 0..3, ks=1]   (8 reads)
#pragma unroll
    for (int j = 0; j < 4; ++j) {
      int cc = wn * 64 + j * 16 + lr;
      b1[j] = *(const bf16x8*)&Bp[cc * 64 + (((4 + lh) ^ (cc & 7)) << 3)];
    }
#pragma unroll
    for (int i = 0; i < 4; ++i) {
      int rr = wm * 128 + i * 16 + lr;
      a0[i] = *(const bf16x8*)&Ap[rr * 64 + (((4 + lh) ^ (rr & 7)) << 3)];
    }
    SB();
    asm volatile("s_waitcnt lgkmcnt(8)" ::: "memory");  // ph1's 4 done
    SB();
    __builtin_amdgcn_s_setprio(1);
#pragma unroll
    for (int i = 0; i < 4; ++i)
#pragma unroll
      for (int j = 0; j < 4; ++j)
        acc[i + 4][j] = __builtin_amdgcn_mfma_f32_16x16x32_bf16(a1[i], b0[j],
                                                                acc[i + 4][j], 0, 0, 0);
    __builtin_amdgcn_s_setprio(0);
    SB();
    // ph3 A-frags: rows 4..7, ks=1   (4 reads)
#pragma unroll
    for (int i = 0; i < 4; ++i) {
      int rr = wm * 128 + (i + 4) * 16 + lr;
      a1[i] = *(const bf16x8*)&Ap[rr * 64 + (((4 + lh) ^ (rr & 7)) << 3)];
    }
    SB();
    asm volatile("s_waitcnt lgkmcnt(4)" ::: "memory");  // ph2's 8 done
    SB();
    __builtin_amdgcn_s_setprio(1);
#pragma unroll
    for (int i = 0; i < 4; ++i)
#pragma unroll
      for (int j = 0; j < 4; ++j)
        acc[i][j] = __builtin_amdgcn_mfma_f32_16x16x32_bf16(a0[i], b1[j],
                                                            acc[i][j], 0, 0, 0);
    __builtin_amdgcn_s_setprio(0);
    SB();
    asm volatile("s_waitcnt lgkmcnt(0)" ::: "memory");  // ph3's 4 done
    SB();
    __builtin_amdgcn_s_setprio(1);
#pragma unroll
    for (int i = 0; i < 4; ++i)
#pragma unroll
      for (int j = 0; j < 4; ++j)
        acc[i + 4][j] = __builtin_amdgcn_mfma_f32_16x16x32_bf16(a1[i], b1[j],
                                                                acc[i + 4][j], 0, 0, 0);
    __builtin_amdgcn_s_setprio(0);
    SB();
    __builtin_amdgcn_s_barrier();  // tail: lgkm==0, buf p reads done everywhere
    SB();
  }

  if (mode == 1) {
#pragma unroll
    for (int i = 0; i < 8; ++i) {
      long row0 = m0 + wm * 128 + i * 16 + lh * 4;
#pragma unroll
      for (int j = 0; j < 4; ++j) {
        int col = (int)n0 + wn * 64 + j * 16 + lr;
#pragma unroll
        for (int jj = 0; jj < 4; ++jj) Cf[(row0 + jj) * 1024 + col] = acc[i][j][jj];
      }
    }
  } else {
    int tok = m0 < 8192;  // M=8448=32*256 token + 1*256 global: tiles never span
#pragma unroll
    for (int i = 0; i < 8; ++i) {
#pragma unroll
      for (int j = 0; j < 4; ++j) {
        int col = (int)n0 + wn * 64 + j * 16 + lr;
        int z = col >> 10, hc = col & 1023;
        int h = hc >> 6, f = hc & 63;
#pragma unroll
        for (int jj = 0; jj < 4; ++jj) {
          long row = m0 + wm * 128 + i * 16 + lh * 4 + jj;
          __bf16 v = (__bf16)acc[i][j][jj];
          if (tok) {
            int b = (int)(row >> 12), l = (int)(row & 4095);
            long bh = b * HN + h;
            if (z == 0) Qt[(bh * SEQ + l) * 64 + f] = v;
            else if (z == 1) Kt[(bh * SEQ + l) * 64 + f] = v;
            else VtT[(bh * 64 + f) * SEQ + l] = v;
          } else {
            int gr = (int)(row - 8192);
            int b = gr >> 7, l = gr & 127;
            long bh = b * HN + h;
            if (z == 0) Qg[(bh * GQ + l) * 64 + f] = v;
            else if (z == 1) Kg[(bh * GQ + l) * 64 + f] = v;
            else VgT[(bh * 64 + f) * GQ + l] = v;
          }
        }
      }
    }
  }
}

// ---------------- fused flash attention, swapped-QK^T softmax ----------------
__global__ __launch_bounds__(256) void attn_kernel(
    const __bf16* __restrict__ Qt, const __bf16* __restrict__ Qg,
    const __bf16* __restrict__ Kg, const __bf16* __restrict__ VgT,
    const __bf16* __restrict__ Kt, const __bf16* __restrict__ VtT,
    const float* __restrict__ mask,
    __bf16* __restrict__ AL, float* __restrict__ Opart, float* __restrict__ Ml) {
  __shared__ __bf16 Ks[2][64 * 64];
  __shared__ __bf16 Vs[2][64 * 64];
  __shared__ __bf16 Ps[128 * 64];

  int bid = blockIdx.x;
  int tid = threadIdx.x, wid = tid >> 6, lane = tid & 63;
  int lr = lane & 15, lh = lane >> 4;

  int isLocal = bid < 1024;
  int unit, q0, tgoff, tokbase, ntiles, pidx = 0;
  if (isLocal) {
    unit = bid >> 5;
    q0 = (bid & 31) << 7;
    tgoff = 0;
    tokbase = q0 & ~(BLK - 1);
    ntiles = 10;
  } else {
    int x = bid - 1024;
    unit = x / NCHUNK;
    int chunk = x - unit * NCHUNK;
    q0 = 0;
    tgoff = chunk * 6;
    tokbase = 0;
    ntiles = 6;
    pidx = x;
  }
  int b = unit >> 4, h = unit & 15;
  long bh = unit;
  const __bf16* Qbase = isLocal ? Qt + (bh * SEQ + q0) * 64 : Qg + bh * GQ * 64;

  bf16x8 qf[2][2];
#pragma unroll
  for (int m = 0; m < 2; m++)
#pragma unroll
    for (int ks = 0; ks < 2; ks++)
      qf[m][ks] = *(const bf16x8*)&Qbase[(wid * 32 + m * 16 + lr) * 64 + ks * 32 + lh * 8];

  float mrun[2], lrun[2];
  f32x4 oacc[2][4];
#pragma unroll
  for (int m = 0; m < 2; m++) {
    mrun[m] = -__builtin_inff();
    lrun[m] = 0.f;
#pragma unroll
    for (int n = 0; n < 4; n++) oacc[m][n] = (f32x4){0.f, 0.f, 0.f, 0.f};
  }

  int c0 = (lane & 7) * 8;
  int ssw = ((wid * 2 + (lane >> 5)) & 3) << 4;
  int rxor = 2 * ((lr >> 2) & 3);

  auto stage = [&](int t, int bb) {
    int tg = t + tgoff;
    int glob = tg < 2;
    int kpos0 = glob ? tg * 64 : tokbase + (tg - 2) * 64;
    const __bf16* Kp = glob ? Kg + (bh * GQ + kpos0) * 64 : Kt + (bh * SEQ + kpos0) * 64;
    const __bf16* Vp = glob ? VgT + bh * 64 * GQ + kpos0 : VtT + bh * 64 * SEQ + kpos0;
    long vstr = glob ? GQ : SEQ;
#pragma unroll
    for (int s = 0; s < 2; ++s) {
      int r = s * 32 + wid * 8 + (lane >> 3);
      GLL16(Kp + (long)r * 64 + (c0 ^ ssw), &Ks[bb][(s * 256 + wid * 64) * 8]);
      GLL16(Vp + (long)r * vstr + (c0 ^ ssw), &Vs[bb][(s * 256 + wid * 64) * 8]);
    }
  };

  stage(0, 0);

  for (int t = 0; t < ntiles; ++t) {
    int bb = t & 1;
    int tg = t + tgoff;
    int glob = tg < 2;
    int kpos0 = glob ? tg * 64 : tokbase + (tg - 2) * 64;

    __syncthreads();
    if (t + 1 < ntiles) stage(t + 1, bb ^ 1);

    f32x4 sacc[4][2];
#pragma unroll
    for (int n = 0; n < 4; n++)
#pragma unroll
      for (int m = 0; m < 2; m++) sacc[n][m] = (f32x4){0.f, 0.f, 0.f, 0.f};
#pragma unroll
    for (int ks = 0; ks < 2; ++ks) {
      bf16x8 kf[4];
#pragma unroll
      for (int n = 0; n < 4; n++)
        kf[n] = *(const bf16x8*)&Ks[bb][(n * 16 + lr) * 64 + (((ks * 4 + lh) ^ rxor) << 3)];
#pragma unroll
      for (int n = 0; n < 4; n++)
#pragma unroll
        for (int m = 0; m < 2; m++)
          sacc[n][m] = __builtin_amdgcn_mfma_f32_16x16x32_bf16(kf[n], qf[m][ks], sacc[n][m], 0, 0, 0);
    }

    float4 mk[4];
    if (glob) {
#pragma unroll
      for (int n = 0; n < 4; n++) mk[n] = (float4){0.f, 0.f, 0.f, 0.f};
    } else {
#pragma unroll
      for (int n = 0; n < 4; n++)
        mk[n] = *(const float4*)&mask[(long)b * SEQ + kpos0 + n * 16 + lh * 4];
    }

    float alpha[2];
#pragma unroll
    for (int m = 0; m < 2; m++) {
      float mx = -__builtin_inff();
#pragma unroll
      for (int n = 0; n < 4; n++) {
        const float* mkp = &mk[n].x;
#pragma unroll
        for (int j = 0; j < 4; j++) {
          float s = sacc[n][m][j] * SCALE + mkp[j];
          sacc[n][m][j] = s;
          mx = fmaxf(mx, s);
        }
      }
      mx = fmaxf(mx, __shfl_xor(mx, 16));
      mx = fmaxf(mx, __shfl_xor(mx, 32));
      float mnew = fmaxf(mrun[m], mx);
      alpha[m] = __expf(mrun[m] - mnew);
      mrun[m] = mnew;
      float rs = 0.f;
#pragma unroll
      for (int n = 0; n < 4; n++) {
#pragma unroll
        for (int j = 0; j < 4; j++) {
          float p = __expf(sacc[n][m][j] - mnew);
          sacc[n][m][j] = p;
          rs += p;
        }
      }
      rs += __shfl_xor(rs, 16);
      rs += __shfl_xor(rs, 32);
      lrun[m] = lrun[m] * alpha[m] + rs;
    }

#pragma unroll
    for (int m = 0; m < 2; m++) {
      int row = wid * 32 + m * 16 + lr;
#pragma unroll
      for (int n = 0; n < 4; n++) {
        bf16x4 pk = {(__bf16)sacc[n][m][0], (__bf16)sacc[n][m][1],
                     (__bf16)sacc[n][m][2], (__bf16)sacc[n][m][3]};
        int g8 = (n * 2 + (lh >> 1)) ^ rxor;
        *(bf16x4*)&Ps[row * 64 + (g8 << 3) + ((lh & 1) << 2)] = pk;
      }
    }

#pragma unroll
    for (int m = 0; m < 2; m++) {
#pragma unroll
      for (int jj = 0; jj < 4; jj++) {
        float a = __shfl(alpha[m], lh * 4 + jj);
#pragma unroll
        for (int n = 0; n < 4; n++) oacc[m][n][jj] *= a;
      }
    }

#pragma unroll
    for (int ks = 0; ks < 2; ++ks) {
      bf16x8 pf[2], vf[4];
#pragma unroll
      for (int m = 0; m < 2; m++) {
        int row = wid * 32 + m * 16 + lr;
        pf[m] = *(const bf16x8*)&Ps[row * 64 + (((ks * 4 + lh) ^ rxor) << 3)];
      }
#pragma unroll
      for (int n = 0; n < 4; n++)
        vf[n] = *(const bf16x8*)&Vs[bb][(n * 16 + lr) * 64 + (((ks * 4 + lh) ^ rxor) << 3)];
#pragma unroll
      for (int m = 0; m < 2; m++)
#pragma unroll
        for (int n = 0; n < 4; n++)
          oacc[m][n] = __builtin_amdgcn_mfma_f32_16x16x32_bf16(pf[m], vf[n], oacc[m][n], 0, 0, 0);
    }
  }

  if (isLocal) {
#pragma unroll
    for (int m = 0; m < 2; m++) {
#pragma unroll
      for (int jj = 0; jj < 4; jj++) {
        float inv = 1.f / __shfl(lrun[m], lh * 4 + jj);
        int row = q0 + wid * 32 + m * 16 + lh * 4 + jj;
#pragma unroll
        for (int n = 0; n < 4; n++)
          AL[((long)b * SEQ + row) * 1024 + h * 64 + n * 16 + lr] =
              (__bf16)(oacc[m][n][jj] * inv);
      }
    }
  } else {
    float* Op = Opart + (long)pidx * (128 * 64);
#pragma unroll
    for (int m = 0; m < 2; m++) {
      int srow = wid * 32 + m * 16 + lr;
      if (lh == 0) {
        Ml[pidx * 256 + srow] = mrun[m];
        Ml[pidx * 256 + 128 + srow] = lrun[m];
      }
#pragma unroll
      for (int jj = 0; jj < 4; jj++) {
        int row = wid * 32 + m * 16 + lh * 4 + jj;
#pragma unroll
        for (int n = 0; n < 4; n++) Op[row * 64 + n * 16 + lr] = oacc[m][n][jj];
      }
    }
  }
}

// ---------------- combine global-attn partials ----------------
__global__ __launch_bounds__(256) void combine_global(
    const float* __restrict__ Opart, const float* __restrict__ Ml,
    __bf16* __restrict__ AG) {
  int unit = blockIdx.x;
  int b = unit >> 4, h = unit & 15;
  int t = threadIdx.x;
  int row = t >> 1, f0 = (t & 1) * 32;

  float mstar = -__builtin_inff();
#pragma unroll
  for (int c = 0; c < NCHUNK; ++c)
    mstar = fmaxf(mstar, Ml[(unit * NCHUNK + c) * 256 + row]);

  float L = 0.f;
  f32x4 acc[8];
#pragma unroll
  for (int k = 0; k < 8; k++) acc[k] = (f32x4){0.f, 0.f, 0.f, 0.f};

  for (int c = 0; c < NCHUNK; ++c) {
    int idx = unit * NCHUNK + c;
    float w = __expf(Ml[idx * 256 + row] - mstar);
    L += w * Ml[idx * 256 + 128 + row];
    const f32x4* src = (const f32x4*)(Opart + ((long)idx * 128 + row) * 64 + f0);
#pragma unroll
    for (int k = 0; k < 8; k++) acc[k] += src[k] * w;
  }
  float inv = 1.f / L;
  __bf16* dst = AG + ((long)b * GQ + row) * 1024 + h * 64 + f0;
#pragma unroll
  for (int k = 0; k < 8; k++) {
    bf16x4 o = {(__bf16)(acc[k][0] * inv), (__bf16)(acc[k][1] * inv),
                (__bf16)(acc[k][2] * inv), (__bf16)(acc[k][3] * inv)};
    *(bf16x4*)(dst + k * 4) = o;
  }
}

extern "C" void kernel_launch(void* const* d_in, const int* in_sizes, int n_in,
                              void* d_out, int out_size, void* d_ws, size_t ws_size,
                              hipStream_t stream) {
  const float* Xt = (const float*)d_in[0];
  const float* Xg = (const float*)d_in[1];
  const float* Msk = (const float*)d_in[2];
  const float* Wq = (const float*)d_in[3];
  const float* Wk = (const float*)d_in[4];
  const float* Wv = (const float*)d_in[5];
  const float* Wo = (const float*)d_in[6];

  float* outF = (float*)d_out;

  char* ws = (char*)d_ws;
  __bf16* Wb = (__bf16*)ws;  ws += (size_t)4 * DM * DM * 2;
  __bf16* XB = (__bf16*)ws;  ws += (size_t)8448 * DM * 2;
  __bf16* Qt = (__bf16*)ws;  ws += (size_t)2 * SEQ * DM * 2;
  __bf16* Kt = (__bf16*)ws;  ws += (size_t)2 * SEQ * DM * 2;
  __bf16* VtT = (__bf16*)ws; ws += (size_t)2 * SEQ * DM * 2;
  __bf16* Qg = (__bf16*)ws;  ws += (size_t)2 * GQ * DM * 2;
  __bf16* Kg = (__bf16*)ws;  ws += (size_t)2 * GQ * DM * 2;
  __bf16* VgT = (__bf16*)ws; ws += (size_t)2 * GQ * DM * 2;
  __bf16* AB = (__bf16*)ws;  ws += (size_t)8448 * DM * 2;

  __bf16* AL = AB;
  __bf16* AG = AB + (size_t)8192 * DM;

  float* Opart = (float*)XB;
  float* Ml = Opart + (long)32 * NCHUNK * 128 * 64;

  cast_w4<<<dim3(1024, 4), 256, 0, stream>>>(Wq, Wk, Wv, Wo, Wb);
  cast_x<<<dim3(8192), 256, 0, stream>>>(Xt, XB);
  cast_x<<<dim3(256), 256, 0, stream>>>(Xg, XB + (size_t)8192 * DM);

  // QKV projection: M=8448, N=3072, K=1024 -> 33 x 12 tiles
  gemm256<<<dim3(396), 512, 0, stream>>>(XB, Wb, Qt, Kt, VtT, Qg, Kg, VgT,
                                         nullptr, 12, 0);

  attn_kernel<<<dim3(1024 + 32 * NCHUNK), 256, 0, stream>>>(
      Qt, Qg, Kg, VgT, Kt, VtT, Msk, AL, Opart, Ml);

  combine_global<<<dim3(32), 256, 0, stream>>>(Opart, Ml, AG);

  // Output projection: M=8448, N=1024 -> 33 x 4 tiles
  gemm256<<<dim3(132), 512, 0, stream>>>(AB, Wb + (size_t)3 * DM * DM,
                                         nullptr, nullptr, nullptr, nullptr, nullptr,
                                         nullptr, outF, 4, 1);
}

// Round 3
// 227.307 us; speedup vs baseline: 1.1348x; 1.0843x over previous
//
#include <hip/hip_runtime.h>
#include <hip/hip_bf16.h>
#include <stdint.h>

typedef __attribute__((ext_vector_type(8))) __bf16 bf16x8;
typedef __attribute__((ext_vector_type(4))) __bf16 bf16x4;
typedef __attribute__((ext_vector_type(4))) float f32x4;

#define HN 16
#define DM 1024
#define GQ 128
#define SEQ 4096
#define BLK 512
#define SCALE 0.125f
#define NCHUNK 11

#define GLL16(g, l) __builtin_amdgcn_global_load_lds( \
    (__attribute__((address_space(1))) void*)(g), \
    (__attribute__((address_space(3))) void*)(l), 16, 0, 0)

// ---------------- casts ----------------
__global__ void cast_w4(const float* __restrict__ w0, const float* __restrict__ w1,
                        const float* __restrict__ w2, const float* __restrict__ w3,
                        __bf16* __restrict__ out) {
  const float* srcs[4] = {w0, w1, w2, w3};
  const float* src = srcs[blockIdx.y];
  int t = blockIdx.x * 256 + threadIdx.x;
  float4 v = ((const float4*)src)[t];
  bf16x4 o = {(__bf16)v.x, (__bf16)v.y, (__bf16)v.z, (__bf16)v.w};
  ((bf16x4*)(out + (size_t)blockIdx.y * (size_t)(DM * DM)))[t] = o;
}

__global__ void cast_x(const float* __restrict__ in, __bf16* __restrict__ out) {
  int t = blockIdx.x * 256 + threadIdx.x;
  float4 v = ((const float4*)in)[t];
  bf16x4 o = {(__bf16)v.x, (__bf16)v.y, (__bf16)v.z, (__bf16)v.w};
  ((bf16x4*)out)[t] = o;
}

// ---------------- 128x128x64 GEMM, m97 structure: single-buffer, 4 blk/CU ---
// 32 KiB LDS (single As/Bs) -> 4 blocks/CU co-resident; inter-block overlap
// hides the per-block vmcnt(0) drain at each tile barrier (m97/m114 regime).
// Zero-conflict XOR-8 involution swizzle (round-0 verified).
__global__ __launch_bounds__(256, 4) void gemm128(
    const __bf16* __restrict__ A, const __bf16* __restrict__ W,
    __bf16* __restrict__ Qt, __bf16* __restrict__ Kt, __bf16* __restrict__ VtT,
    __bf16* __restrict__ Qg, __bf16* __restrict__ Kg, __bf16* __restrict__ VgT,
    float* __restrict__ Cf, int NT, int mode) {
  __shared__ __bf16 As[128 * 64];
  __shared__ __bf16 Bs[128 * 64];
  int tid = threadIdx.x;
  int lane = tid & 63, wid = tid >> 6;
  int lr = lane & 15, lh = lane >> 4;
  int wm = wid >> 1, wn = wid & 1;

  int nwg = gridDim.x;
  int q = nwg >> 3, r = nwg & 7;
  int xcd = blockIdx.x & 7, loc = blockIdx.x >> 3;
  int swz = (xcd < r ? xcd * (q + 1) : r * (q + 1) + (xcd - r) * q) + loc;
  int bm = swz / NT, bn = swz - bm * NT;
  long m0 = (long)bm * 128, n0 = (long)bn * 128;
  const __bf16* Ab = A + m0 * 1024;
  const __bf16* Wb2 = W + n0 * 1024;

  int srow = tid >> 3;                          // 0..31, 8 threads/row
  int scol = (((tid & 7) ^ (srow & 7)) << 3);   // pre-swizzled source granule

  f32x4 acc[4][4];
#pragma unroll
  for (int i = 0; i < 4; ++i)
#pragma unroll
    for (int j = 0; j < 4; ++j) acc[i][j] = (f32x4){0.f, 0.f, 0.f, 0.f};

#pragma unroll 1
  for (int kt = 0; kt < 16; ++kt) {
    int k0 = kt * 64;
#pragma unroll
    for (int c = 0; c < 4; ++c) {
      int row = srow + c * 32;
      GLL16(Ab + (long)row * 1024 + k0 + scol, &As[(c * 256 + tid) * 8]);
    }
#pragma unroll
    for (int c = 0; c < 4; ++c) {
      int row = srow + c * 32;
      GLL16(Wb2 + (long)row * 1024 + k0 + scol, &Bs[(c * 256 + tid) * 8]);
    }
    asm volatile("s_waitcnt vmcnt(0)" ::: "memory");
    __syncthreads();

#pragma unroll
    for (int ks = 0; ks < 2; ++ks) {
      bf16x8 af[4], bfr[4];
#pragma unroll
      for (int i = 0; i < 4; ++i) {
        int rr = wm * 64 + i * 16 + lr;
        af[i] = *(const bf16x8*)&As[rr * 64 + (((ks * 4 + lh) ^ (rr & 7)) << 3)];
        int cc = wn * 64 + i * 16 + lr;
        bfr[i] = *(const bf16x8*)&Bs[cc * 64 + (((ks * 4 + lh) ^ (cc & 7)) << 3)];
      }
#pragma unroll
      for (int i = 0; i < 4; ++i)
#pragma unroll
        for (int j = 0; j < 4; ++j)
          acc[i][j] = __builtin_amdgcn_mfma_f32_16x16x32_bf16(af[i], bfr[j],
                                                              acc[i][j], 0, 0, 0);
    }
    __syncthreads();
  }

  if (mode == 1) {
#pragma unroll
    for (int i = 0; i < 4; ++i) {
      long row0 = m0 + wm * 64 + i * 16 + lh * 4;
#pragma unroll
      for (int j = 0; j < 4; ++j) {
        int col = (int)n0 + wn * 64 + j * 16 + lr;
#pragma unroll
        for (int jj = 0; jj < 4; ++jj) Cf[(row0 + jj) * 1024 + col] = acc[i][j][jj];
      }
    }
  } else {
    int tok = m0 < 8192;
#pragma unroll
    for (int i = 0; i < 4; ++i) {
#pragma unroll
      for (int j = 0; j < 4; ++j) {
        int col = (int)n0 + wn * 64 + j * 16 + lr;
        int z = col >> 10, hc = col & 1023;
        int h = hc >> 6, f = hc & 63;
#pragma unroll
        for (int jj = 0; jj < 4; ++jj) {
          long row = m0 + wm * 64 + i * 16 + lh * 4 + jj;
          __bf16 v = (__bf16)acc[i][j][jj];
          if (tok) {
            int b = (int)(row >> 12), l = (int)(row & 4095);
            long bh = b * HN + h;
            if (z == 0) Qt[(bh * SEQ + l) * 64 + f] = v;
            else if (z == 1) Kt[(bh * SEQ + l) * 64 + f] = v;
            else VtT[(bh * 64 + f) * SEQ + l] = v;
          } else {
            int gr = (int)(row - 8192);
            int b = gr >> 7, l = gr & 127;
            long bh = b * HN + h;
            if (z == 0) Qg[(bh * GQ + l) * 64 + f] = v;
            else if (z == 1) Kg[(bh * GQ + l) * 64 + f] = v;
            else VgT[(bh * 64 + f) * GQ + l] = v;
          }
        }
      }
    }
  }
}

// ---------------- fused flash attention, swapped-QK^T softmax ----------------
__global__ __launch_bounds__(256) void attn_kernel(
    const __bf16* __restrict__ Qt, const __bf16* __restrict__ Qg,
    const __bf16* __restrict__ Kg, const __bf16* __restrict__ VgT,
    const __bf16* __restrict__ Kt, const __bf16* __restrict__ VtT,
    const float* __restrict__ mask,
    __bf16* __restrict__ AL, float* __restrict__ Opart, float* __restrict__ Ml) {
  __shared__ __bf16 Ks[2][64 * 64];
  __shared__ __bf16 Vs[2][64 * 64];
  __shared__ __bf16 Ps[128 * 64];

  int bid = blockIdx.x;
  int tid = threadIdx.x, wid = tid >> 6, lane = tid & 63;
  int lr = lane & 15, lh = lane >> 4;

  int isLocal = bid < 1024;
  int unit, q0, tgoff, tokbase, ntiles, pidx = 0;
  if (isLocal) {
    unit = bid >> 5;
    q0 = (bid & 31) << 7;
    tgoff = 0;
    tokbase = q0 & ~(BLK - 1);
    ntiles = 10;
  } else {
    int x = bid - 1024;
    unit = x / NCHUNK;
    int chunk = x - unit * NCHUNK;
    q0 = 0;
    tgoff = chunk * 6;
    tokbase = 0;
    ntiles = 6;
    pidx = x;
  }
  int b = unit >> 4, h = unit & 15;
  long bh = unit;
  const __bf16* Qbase = isLocal ? Qt + (bh * SEQ + q0) * 64 : Qg + bh * GQ * 64;

  bf16x8 qf[2][2];
#pragma unroll
  for (int m = 0; m < 2; m++)
#pragma unroll
    for (int ks = 0; ks < 2; ks++)
      qf[m][ks] = *(const bf16x8*)&Qbase[(wid * 32 + m * 16 + lr) * 64 + ks * 32 + lh * 8];

  float mrun[2], lrun[2];
  f32x4 oacc[2][4];
#pragma unroll
  for (int m = 0; m < 2; m++) {
    mrun[m] = -__builtin_inff();
    lrun[m] = 0.f;
#pragma unroll
    for (int n = 0; n < 4; n++) oacc[m][n] = (f32x4){0.f, 0.f, 0.f, 0.f};
  }

  int c0 = (lane & 7) * 8;
  int ssw = ((wid * 2 + (lane >> 5)) & 3) << 4;
  int rxor = 2 * ((lr >> 2) & 3);

  auto stage = [&](int t, int bb) {
    int tg = t + tgoff;
    int glob = tg < 2;
    int kpos0 = glob ? tg * 64 : tokbase + (tg - 2) * 64;
    const __bf16* Kp = glob ? Kg + (bh * GQ + kpos0) * 64 : Kt + (bh * SEQ + kpos0) * 64;
    const __bf16* Vp = glob ? VgT + bh * 64 * GQ + kpos0 : VtT + bh * 64 * SEQ + kpos0;
    long vstr = glob ? GQ : SEQ;
#pragma unroll
    for (int s = 0; s < 2; ++s) {
      int r = s * 32 + wid * 8 + (lane >> 3);
      GLL16(Kp + (long)r * 64 + (c0 ^ ssw), &Ks[bb][(s * 256 + wid * 64) * 8]);
      GLL16(Vp + (long)r * vstr + (c0 ^ ssw), &Vs[bb][(s * 256 + wid * 64) * 8]);
    }
  };

  stage(0, 0);

  for (int t = 0; t < ntiles; ++t) {
    int bb = t & 1;
    int tg = t + tgoff;
    int glob = tg < 2;
    int kpos0 = glob ? tg * 64 : tokbase + (tg - 2) * 64;

    __syncthreads();
    if (t + 1 < ntiles) stage(t + 1, bb ^ 1);

    f32x4 sacc[4][2];
#pragma unroll
    for (int n = 0; n < 4; n++)
#pragma unroll
      for (int m = 0; m < 2; m++) sacc[n][m] = (f32x4){0.f, 0.f, 0.f, 0.f};
#pragma unroll
    for (int ks = 0; ks < 2; ++ks) {
      bf16x8 kf[4];
#pragma unroll
      for (int n = 0; n < 4; n++)
        kf[n] = *(const bf16x8*)&Ks[bb][(n * 16 + lr) * 64 + (((ks * 4 + lh) ^ rxor) << 3)];
#pragma unroll
      for (int n = 0; n < 4; n++)
#pragma unroll
        for (int m = 0; m < 2; m++)
          sacc[n][m] = __builtin_amdgcn_mfma_f32_16x16x32_bf16(kf[n], qf[m][ks], sacc[n][m], 0, 0, 0);
    }

    float4 mk[4];
    if (glob) {
#pragma unroll
      for (int n = 0; n < 4; n++) mk[n] = (float4){0.f, 0.f, 0.f, 0.f};
    } else {
#pragma unroll
      for (int n = 0; n < 4; n++)
        mk[n] = *(const float4*)&mask[(long)b * SEQ + kpos0 + n * 16 + lh * 4];
    }

    float alpha[2];
#pragma unroll
    for (int m = 0; m < 2; m++) {
      float mx = -__builtin_inff();
#pragma unroll
      for (int n = 0; n < 4; n++) {
        const float* mkp = &mk[n].x;
#pragma unroll
        for (int j = 0; j < 4; j++) {
          float s = sacc[n][m][j] * SCALE + mkp[j];
          sacc[n][m][j] = s;
          mx = fmaxf(mx, s);
        }
      }
      mx = fmaxf(mx, __shfl_xor(mx, 16));
      mx = fmaxf(mx, __shfl_xor(mx, 32));
      float mnew = fmaxf(mrun[m], mx);
      alpha[m] = __expf(mrun[m] - mnew);
      mrun[m] = mnew;
      float rs = 0.f;
#pragma unroll
      for (int n = 0; n < 4; n++) {
#pragma unroll
        for (int j = 0; j < 4; j++) {
          float p = __expf(sacc[n][m][j] - mnew);
          sacc[n][m][j] = p;
          rs += p;
        }
      }
      rs += __shfl_xor(rs, 16);
      rs += __shfl_xor(rs, 32);
      lrun[m] = lrun[m] * alpha[m] + rs;
    }

#pragma unroll
    for (int m = 0; m < 2; m++) {
      int row = wid * 32 + m * 16 + lr;
#pragma unroll
      for (int n = 0; n < 4; n++) {
        bf16x4 pk = {(__bf16)sacc[n][m][0], (__bf16)sacc[n][m][1],
                     (__bf16)sacc[n][m][2], (__bf16)sacc[n][m][3]};
        int g8 = (n * 2 + (lh >> 1)) ^ rxor;
        *(bf16x4*)&Ps[row * 64 + (g8 << 3) + ((lh & 1) << 2)] = pk;
      }
    }

#pragma unroll
    for (int m = 0; m < 2; m++) {
#pragma unroll
      for (int jj = 0; jj < 4; jj++) {
        float a = __shfl(alpha[m], lh * 4 + jj);
#pragma unroll
        for (int n = 0; n < 4; n++) oacc[m][n][jj] *= a;
      }
    }

#pragma unroll
    for (int ks = 0; ks < 2; ++ks) {
      bf16x8 pf[2], vf[4];
#pragma unroll
      for (int m = 0; m < 2; m++) {
        int row = wid * 32 + m * 16 + lr;
        pf[m] = *(const bf16x8*)&Ps[row * 64 + (((ks * 4 + lh) ^ rxor) << 3)];
      }
#pragma unroll
      for (int n = 0; n < 4; n++)
        vf[n] = *(const bf16x8*)&Vs[bb][(n * 16 + lr) * 64 + (((ks * 4 + lh) ^ rxor) << 3)];
#pragma unroll
      for (int m = 0; m < 2; m++)
#pragma unroll
        for (int n = 0; n < 4; n++)
          oacc[m][n] = __builtin_amdgcn_mfma_f32_16x16x32_bf16(pf[m], vf[n], oacc[m][n], 0, 0, 0);
    }
  }

  if (isLocal) {
#pragma unroll
    for (int m = 0; m < 2; m++) {
#pragma unroll
      for (int jj = 0; jj < 4; jj++) {
        float inv = 1.f / __shfl(lrun[m], lh * 4 + jj);
        int row = q0 + wid * 32 + m * 16 + lh * 4 + jj;
#pragma unroll
        for (int n = 0; n < 4; n++)
          AL[((long)b * SEQ + row) * 1024 + h * 64 + n * 16 + lr] =
              (__bf16)(oacc[m][n][jj] * inv);
      }
    }
  } else {
    float* Op = Opart + (long)pidx * (128 * 64);
#pragma unroll
    for (int m = 0; m < 2; m++) {
      int srow = wid * 32 + m * 16 + lr;
      if (lh == 0) {
        Ml[pidx * 256 + srow] = mrun[m];
        Ml[pidx * 256 + 128 + srow] = lrun[m];
      }
#pragma unroll
      for (int jj = 0; jj < 4; jj++) {
        int row = wid * 32 + m * 16 + lh * 4 + jj;
#pragma unroll
        for (int n = 0; n < 4; n++) Op[row * 64 + n * 16 + lr] = oacc[m][n][jj];
      }
    }
  }
}

// ---------------- combine global-attn partials ----------------
__global__ __launch_bounds__(256) void combine_global(
    const float* __restrict__ Opart, const float* __restrict__ Ml,
    __bf16* __restrict__ AG) {
  int unit = blockIdx.x;
  int b = unit >> 4, h = unit & 15;
  int t = threadIdx.x;
  int row = t >> 1, f0 = (t & 1) * 32;

  float mstar = -__builtin_inff();
#pragma unroll
  for (int c = 0; c < NCHUNK; ++c)
    mstar = fmaxf(mstar, Ml[(unit * NCHUNK + c) * 256 + row]);

  float L = 0.f;
  f32x4 acc[8];
#pragma unroll
  for (int k = 0; k < 8; k++) acc[k] = (f32x4){0.f, 0.f, 0.f, 0.f};

  for (int c = 0; c < NCHUNK; ++c) {
    int idx = unit * NCHUNK + c;
    float w = __expf(Ml[idx * 256 + row] - mstar);
    L += w * Ml[idx * 256 + 128 + row];
    const f32x4* src = (const f32x4*)(Opart + ((long)idx * 128 + row) * 64 + f0);
#pragma unroll
    for (int k = 0; k < 8; k++) acc[k] += src[k] * w;
  }
  float inv = 1.f / L;
  __bf16* dst = AG + ((long)b * GQ + row) * 1024 + h * 64 + f0;
#pragma unroll
  for (int k = 0; k < 8; k++) {
    bf16x4 o = {(__bf16)(acc[k][0] * inv), (__bf16)(acc[k][1] * inv),
                (__bf16)(acc[k][2] * inv), (__bf16)(acc[k][3] * inv)};
    *(bf16x4*)(dst + k * 4) = o;
  }
}

extern "C" void kernel_launch(void* const* d_in, const int* in_sizes, int n_in,
                              void* d_out, int out_size, void* d_ws, size_t ws_size,
                              hipStream_t stream) {
  const float* Xt = (const float*)d_in[0];
  const float* Xg = (const float*)d_in[1];
  const float* Msk = (const float*)d_in[2];
  const float* Wq = (const float*)d_in[3];
  const float* Wk = (const float*)d_in[4];
  const float* Wv = (const float*)d_in[5];
  const float* Wo = (const float*)d_in[6];

  float* outF = (float*)d_out;

  char* ws = (char*)d_ws;
  __bf16* Wb = (__bf16*)ws;  ws += (size_t)4 * DM * DM * 2;
  __bf16* XB = (__bf16*)ws;  ws += (size_t)8448 * DM * 2;
  __bf16* Qt = (__bf16*)ws;  ws += (size_t)2 * SEQ * DM * 2;
  __bf16* Kt = (__bf16*)ws;  ws += (size_t)2 * SEQ * DM * 2;
  __bf16* VtT = (__bf16*)ws; ws += (size_t)2 * SEQ * DM * 2;
  __bf16* Qg = (__bf16*)ws;  ws += (size_t)2 * GQ * DM * 2;
  __bf16* Kg = (__bf16*)ws;  ws += (size_t)2 * GQ * DM * 2;
  __bf16* VgT = (__bf16*)ws; ws += (size_t)2 * GQ * DM * 2;
  __bf16* AB = (__bf16*)ws;  ws += (size_t)8448 * DM * 2;

  __bf16* AL = AB;
  __bf16* AG = AB + (size_t)8192 * DM;

  float* Opart = (float*)XB;
  float* Ml = Opart + (long)32 * NCHUNK * 128 * 64;

  cast_w4<<<dim3(1024, 4), 256, 0, stream>>>(Wq, Wk, Wv, Wo, Wb);
  cast_x<<<dim3(8192), 256, 0, stream>>>(Xt, XB);
  cast_x<<<dim3(256), 256, 0, stream>>>(Xg, XB + (size_t)8192 * DM);

  // QKV projection: M=8448, N=3072 -> 66 x 24 tiles
  gemm128<<<dim3(1584), 256, 0, stream>>>(XB, Wb, Qt, Kt, VtT, Qg, Kg, VgT,
                                          nullptr, 24, 0);

  attn_kernel<<<dim3(1024 + 32 * NCHUNK), 256, 0, stream>>>(
      Qt, Qg, Kg, VgT, Kt, VtT, Msk, AL, Opart, Ml);

  combine_global<<<dim3(32), 256, 0, stream>>>(Opart, Ml, AG);

  // Output projection: M=8448, N=1024 -> 66 x 8 tiles
  gemm128<<<dim3(528), 256, 0, stream>>>(AB, Wb + (size_t)3 * DM * DM,
                                         nullptr, nullptr, nullptr, nullptr, nullptr,
                                         nullptr, outF, 8, 1);
}